// Round 3
// baseline (2313.727 us; speedup 1.0000x reference)
//
#include <hip/hip_runtime.h>
#include <hip/hip_bf16.h>

#define H     1152
#define H3    3456
#define H6    6912
#define NTOK  1024
#define NB    16
#define NHEAD 16
#define HDIM  72
#define MLPD  4608
#define ROWS  (NB*NTOK)   // 16384

typedef __hip_bfloat16 bf16;
typedef float f32x4 __attribute__((ext_vector_type(4)));
typedef __bf16 bf16x8 __attribute__((ext_vector_type(8)));
typedef const __attribute__((address_space(1))) void* gptr_as1;
typedef __attribute__((address_space(3))) void* lptr_as3;

__device__ __forceinline__ float b2f(bf16 v){ return __bfloat162float(v); }
__device__ __forceinline__ bf16  f2b(float v){ return __float2bfloat16(v); }

// ---------------- mod = swish(c) @ w_mod + b_mod  (16 x 6912, all f32) ----------------
// swish(c) staged in LDS once per block; w_mod read exactly once across the grid.
__global__ __launch_bounds__(256) void mod_kernel(const float* __restrict__ c,
                                                  const float* __restrict__ w_mod,
                                                  const float* __restrict__ b_mod,
                                                  float* __restrict__ mod) {
    __shared__ float sw[NB*H];                    // 73728 B
    for (int i = threadIdx.x; i < NB*H; i += 256) {
        float cv = c[i];
        sw[i] = cv / (1.f + __expf(-cv));
    }
    __syncthreads();
    const int col = blockIdx.x*256 + threadIdx.x; // H6 = 27*256 exact
    float acc[NB];
    #pragma unroll
    for (int b = 0; b < NB; ++b) acc[b] = 0.f;
    for (int k = 0; k < H; ++k) {
        float wv = w_mod[(long)k*H6 + col];
        #pragma unroll
        for (int b = 0; b < NB; ++b) acc[b] += sw[b*H + k] * wv;
    }
    const float bm = b_mod[col];
    #pragma unroll
    for (int b = 0; b < NB; ++b) mod[b*H6 + col] = acc[b] + bm;
}

// ---------------- row LN + adaLN modulate: out[local bf16] = LN(x_f32[global])*(1+sc)+sh ----------------
__global__ __launch_bounds__(256) void ln_mod_kernel(const float* __restrict__ xin,   // global base (f32)
                                                     const float* __restrict__ mod,
                                                     int sh_off, int sc_off,
                                                     bf16* __restrict__ out,          // chunk-local base
                                                     int row0) {
    const int lrow = blockIdx.x;
    const long grow = (long)row0 + lrow;
    const int b = (int)(grow >> 10);
    const int tid = threadIdx.x;
    const long ibase = grow * H;
    const long obase = (long)lrow * H;
    __shared__ float sred[8];
    float vals[5];
    float sum = 0.f, sq = 0.f;
    #pragma unroll
    for (int i = 0; i < 5; ++i) {
        int cidx = i*256 + tid;
        float v = 0.f;
        if (cidx < H) v = xin[ibase+cidx];
        vals[i] = v; sum += v; sq += v*v;
    }
    #pragma unroll
    for (int off = 32; off > 0; off >>= 1) { sum += __shfl_down(sum, off); sq += __shfl_down(sq, off); }
    int wave = tid >> 6, lane = tid & 63;
    if (lane == 0) { sred[wave] = sum; sred[4+wave] = sq; }
    __syncthreads();
    if (tid == 0) {
        sred[0] = sred[0]+sred[1]+sred[2]+sred[3];
        sred[4] = sred[4]+sred[5]+sred[6]+sred[7];
    }
    __syncthreads();
    float mean = sred[0] * (1.f/H);
    float var  = sred[4] * (1.f/H) - mean*mean;
    float rstd = rsqrtf(var + 1e-6f);
    const float* mrow = mod + b*H6;
    #pragma unroll
    for (int i = 0; i < 5; ++i) {
        int cidx = i*256 + tid;
        if (cidx < H) {
            float y = (vals[i]-mean)*rstd;
            out[obase+cidx] = f2b(y * (1.f + mrow[sc_off+cidx]) + mrow[sh_off+cidx]);
        }
    }
}

// ---------------- f32 -> bf16 transpose (R,C)->(C,R), dims multiple of 32 ----------------
__global__ __launch_bounds__(256) void transpose_kernel(const float* __restrict__ in,
                                                        bf16* __restrict__ out, int R, int C) {
    __shared__ bf16 tile[32][33];
    int c0 = blockIdx.x*32, r0 = blockIdx.y*32;
    int tx = threadIdx.x & 31, ty = threadIdx.x >> 5;
    for (int j = ty; j < 32; j += 8) tile[j][tx] = f2b(in[(long)(r0+j)*C + c0 + tx]);
    __syncthreads();
    for (int j = ty; j < 32; j += 8) out[(long)(c0+j)*R + r0 + tx] = tile[tx][j];
}

// ---------------- m97-style GEMM: A[local M,K]bf16 @ BT[N,K]^T bf16 + bias(f32) ----------------
// EPI 0: C[local] = acc+bias (bf16)
// EPI 1: C[local] = gelu(acc+bias) (bf16)
// EPI 2: Cf[global,f32] = res_f32[global] + gate*(acc+bias)
template<int EPI>
__global__ __launch_bounds__(256) void gemm_bt(const bf16* __restrict__ A, const bf16* __restrict__ BT,
                                               const float* __restrict__ bias,
                                               const float* __restrict__ res, const float* __restrict__ gate,
                                               bf16* __restrict__ C, float* __restrict__ Cf,
                                               int M, int N, int K, int row0) {
    __shared__ __align__(16) bf16 As[128*64];
    __shared__ __align__(16) bf16 Bs[128*64];
    const int tid  = threadIdx.x;
    const int wave = tid >> 6, lane = tid & 63;
    const int wm = wave & 1, wn = wave >> 1;
    const int col = lane & 15, quad = lane >> 4;
    f32x4 acc[4][4];
    #pragma unroll
    for (int i = 0; i < 4; ++i)
        #pragma unroll
        for (int j = 0; j < 4; ++j) acc[i][j] = (f32x4){0.f,0.f,0.f,0.f};

    const long arow0 = (long)blockIdx.y * 128;
    const long brow0 = (long)blockIdx.x * 128;
    const int  srow  = tid >> 3;
    const int  scol  = (tid & 7) * 8;
    const bf16* Ag = A + (arow0 + srow)*(long)K + scol;
    const bf16* Bg = BT + (brow0 + srow)*(long)K + scol;
    bf16* Asl = As + tid*8;
    bf16* Bsl = Bs + tid*8;

    for (int k0 = 0; k0 < K; k0 += 64) {
        __syncthreads();
        #pragma unroll
        for (int i = 0; i < 4; ++i) {
            __builtin_amdgcn_global_load_lds((gptr_as1)(Ag + (long)i*32*K + k0), (lptr_as3)(Asl + i*2048), 16, 0, 0);
            __builtin_amdgcn_global_load_lds((gptr_as1)(Bg + (long)i*32*K + k0), (lptr_as3)(Bsl + i*2048), 16, 0, 0);
        }
        __syncthreads();
        #pragma unroll
        for (int kk = 0; kk < 64; kk += 32) {
            bf16x8 af[4], bfr[4];
            #pragma unroll
            for (int mt = 0; mt < 4; ++mt) af[mt]  = *(const bf16x8*)&As[(wm*64+mt*16+col)*64 + kk + quad*8];
            #pragma unroll
            for (int nt = 0; nt < 4; ++nt) bfr[nt] = *(const bf16x8*)&Bs[(wn*64+nt*16+col)*64 + kk + quad*8];
            #pragma unroll
            for (int mt = 0; mt < 4; ++mt)
                #pragma unroll
                for (int nt = 0; nt < 4; ++nt)
                    acc[mt][nt] = __builtin_amdgcn_mfma_f32_16x16x32_bf16(af[mt], bfr[nt], acc[mt][nt], 0, 0, 0);
        }
    }

    #pragma unroll
    for (int mt = 0; mt < 4; ++mt) {
        #pragma unroll
        for (int nt = 0; nt < 4; ++nt) {
            const int colg = (int)brow0 + wn*64 + nt*16 + col;
            const float bv = bias[colg];
            #pragma unroll
            for (int r = 0; r < 4; ++r) {
                const long rowg = arow0 + wm*64 + mt*16 + quad*4 + r;
                float v = acc[mt][nt][r] + bv;
                if (EPI == 1) {
                    v = 0.5f*v*(1.f + tanhf(0.7978845608028654f*(v + 0.044715f*v*v*v)));
                    C[rowg*(long)N + colg] = f2b(v);
                } else if (EPI == 2) {
                    const long grow = row0 + rowg;
                    float g = gate[(int)(grow>>10)*H6 + colg];
                    Cf[grow*(long)N + colg] = res[grow*(long)N + colg] + g*v;
                } else {
                    C[rowg*(long)N + colg] = f2b(v);
                }
            }
        }
    }
}

// ---------------- per-head LN of q,k (dim 72, bf16 in/out) -> padded [b'][NH][N][96] ----------------
__device__ __forceinline__ void ln72(const bf16* __restrict__ src, const float* __restrict__ gw,
                                     float scale, bf16* __restrict__ dst, int lane) {
    const int i1 = 64 + (lane & 7);
    float e0 = b2f(src[lane]);
    float e1 = (lane < 8) ? b2f(src[i1]) : 0.f;
    float s = e0 + e1;
    #pragma unroll
    for (int off = 32; off > 0; off >>= 1) s += __shfl_xor(s, off);
    float mean = s * (1.f/72.f);
    float d0 = e0 - mean;
    float d1 = (lane < 8) ? (e1 - mean) : 0.f;
    float sq = d0*d0 + d1*d1;
    #pragma unroll
    for (int off = 32; off > 0; off >>= 1) sq += __shfl_xor(sq, off);
    float rstd = rsqrtf(sq*(1.f/72.f) + 1e-6f);
    dst[lane] = f2b(d0*rstd*gw[lane]*scale);
    if (lane < 32) {
        float y1 = (lane < 8) ? d1*rstd*gw[i1]*scale : 0.f;
        dst[64+lane] = f2b(y1);
    }
}

__global__ __launch_bounds__(256) void qk_ln_kernel(const bf16* __restrict__ qkv,  // chunk-local
                                                    const float* __restrict__ g_q, const float* __restrict__ g_k,
                                                    bf16* __restrict__ qln, bf16* __restrict__ kln) {
    const int wave = threadIdx.x >> 6, lane = threadIdx.x & 63;
    const long g  = (long)blockIdx.x*4 + wave;     // < Bc*NHEAD*NTOK
    const int  n  = (int)(g & 1023);
    const long bh = g >> 10;                        // local b*16 + h
    const int  h  = (int)(bh & 15);
    const int  b  = (int)(bh >> 4);
    const bf16* src = qkv + ((long)b*NTOK + n)*H3 + h*HDIM;
    ln72(src,     g_q, 0.11785113019775793f, qln + (bh*NTOK + n)*96, lane);   // q * HD^-0.5
    ln72(src + H, g_k, 1.f,                  kln + (bh*NTOK + n)*96, lane);
}

// ---------------- V -> VT [b'][NH][80][NTOK] (pad rows 72..79 = 0), bf16 ----------------
__global__ __launch_bounds__(256) void v_transpose_kernel(const bf16* __restrict__ qkv, bf16* __restrict__ vt) {
    const int n0 = blockIdx.x*64;
    const int h = blockIdx.y, b = blockIdx.z;      // b local
    __shared__ bf16 tile[64][80];
    const long srcbase = ((long)b*NTOK + n0)*H3 + 2*H + h*HDIM;
    for (int idx = threadIdx.x; idx < 64*72; idx += 256) {
        int n = idx/72, d = idx - n*72;
        tile[n][d] = qkv[srcbase + (long)n*H3 + d];
    }
    for (int idx = threadIdx.x; idx < 64*8; idx += 256) {
        int n = idx >> 3, d = idx & 7;
        tile[n][72+d] = f2b(0.f);
    }
    __syncthreads();
    const long dstbase = ((long)(b*NHEAD + h)*80)*NTOK + n0;
    for (int idx = threadIdx.x; idx < 80*64; idx += 256) {
        int d = idx >> 6, n = idx & 63;
        vt[dstbase + (long)d*NTOK + n] = tile[n][d];
    }
}

// ---------------- flash attention: wave = 16 q rows, kv tiles of 32 (chunk-local, bf16) ----------------
__global__ __launch_bounds__(256) void attn_kernel(const bf16* __restrict__ qln, const bf16* __restrict__ kln,
                                                   const bf16* __restrict__ vt, bf16* __restrict__ o) {
    const int wave = threadIdx.x >> 6, lane = threadIdx.x & 63;
    const int col = lane & 15, quad = lane >> 4;
    const int b = blockIdx.z, h = blockIdx.y;      // b local
    const long bh = b*NHEAD + h;
    const int q0 = blockIdx.x*64 + wave*16;
    const bf16* qb = qln + bh*NTOK*96;
    const bf16* kb = kln + bh*NTOK*96;
    const bf16* vb = vt  + bh*80*NTOK;
    __shared__ __align__(16) bf16 Pl[4][16*32];
    bf16* pw = &Pl[wave][0];

    bf16x8 qf[3];
    #pragma unroll
    for (int ks = 0; ks < 3; ++ks) qf[ks] = *(const bf16x8*)&qb[(q0+col)*96 + ks*32 + quad*8];

    f32x4 oacc[5];
    #pragma unroll
    for (int i = 0; i < 5; ++i) oacc[i] = (f32x4){0.f,0.f,0.f,0.f};
    float mrow[4], lrow[4];
    #pragma unroll
    for (int r = 0; r < 4; ++r) { mrow[r] = -1e30f; lrow[r] = 0.f; }

    for (int kv0 = 0; kv0 < NTOK; kv0 += 32) {
        f32x4 s0 = (f32x4){0.f,0.f,0.f,0.f}, s1 = (f32x4){0.f,0.f,0.f,0.f};
        #pragma unroll
        for (int ks = 0; ks < 3; ++ks) {
            bf16x8 k0f = *(const bf16x8*)&kb[(kv0+col)*96    + ks*32 + quad*8];
            bf16x8 k1f = *(const bf16x8*)&kb[(kv0+16+col)*96 + ks*32 + quad*8];
            s0 = __builtin_amdgcn_mfma_f32_16x16x32_bf16(qf[ks], k0f, s0, 0, 0, 0);
            s1 = __builtin_amdgcn_mfma_f32_16x16x32_bf16(qf[ks], k1f, s1, 0, 0, 0);
        }
        float alpha[4];
        #pragma unroll
        for (int r = 0; r < 4; ++r) {
            float tm = fmaxf(s0[r], s1[r]);
            #pragma unroll
            for (int off = 1; off < 16; off <<= 1) tm = fmaxf(tm, __shfl_xor(tm, off));
            float mn = fmaxf(mrow[r], tm);
            alpha[r] = __expf(mrow[r] - mn);
            float p0 = __expf(s0[r] - mn);
            float p1 = __expf(s1[r] - mn);
            float ts = p0 + p1;
            #pragma unroll
            for (int off = 1; off < 16; off <<= 1) ts += __shfl_xor(ts, off);
            lrow[r] = lrow[r]*alpha[r] + ts;
            mrow[r] = mn;
            pw[(quad*4+r)*32 + col]      = f2b(p0);
            pw[(quad*4+r)*32 + 16 + col] = f2b(p1);
        }
        #pragma unroll
        for (int i = 0; i < 5; ++i)
            #pragma unroll
            for (int r = 0; r < 4; ++r) oacc[i][r] *= alpha[r];
        asm volatile("s_waitcnt lgkmcnt(0)" ::: "memory");
        bf16x8 pf = *(const bf16x8*)&pw[col*32 + quad*8];
        #pragma unroll
        for (int nt = 0; nt < 5; ++nt) {
            bf16x8 vf = *(const bf16x8*)&vb[(nt*16+col)*NTOK + kv0 + quad*8];
            oacc[nt] = __builtin_amdgcn_mfma_f32_16x16x32_bf16(pf, vf, oacc[nt], 0, 0, 0);
        }
    }
    float inv[4];
    #pragma unroll
    for (int r = 0; r < 4; ++r) inv[r] = 1.f / lrow[r];
    #pragma unroll
    for (int nt = 0; nt < 5; ++nt) {
        int d = nt*16 + col;
        if (d < HDIM) {
            #pragma unroll
            for (int r = 0; r < 4; ++r) {
                int qrow = q0 + quad*4 + r;
                o[((long)b*NTOK + qrow)*H + h*HDIM + d] = f2b(oacc[nt][r]*inv[r]);
            }
        }
    }
}

extern "C" void kernel_launch(void* const* d_in, const int* in_sizes, int n_in,
                              void* d_out, int out_size, void* d_ws, size_t ws_size,
                              hipStream_t stream) {
    const float* x      = (const float*)d_in[0];
    const float* c      = (const float*)d_in[1];
    const float* w_mod  = (const float*)d_in[2];
    const float* b_mod  = (const float*)d_in[3];
    const float* w_qkv  = (const float*)d_in[4];
    const float* b_qkv  = (const float*)d_in[5];
    const float* g_q    = (const float*)d_in[6];
    const float* g_k    = (const float*)d_in[7];
    const float* w_proj = (const float*)d_in[8];
    const float* b_proj = (const float*)d_in[9];
    const float* w1     = (const float*)d_in[10];
    const float* b1     = (const float*)d_in[11];
    const float* w2     = (const float*)d_in[12];
    const float* b2     = (const float*)d_in[13];
    float* out = (float*)d_out;   // f32; also serves as x1 (residual after attn branch)

    // ---- workspace layout (runtime-sized, chunked row pipeline) ----
    char* ws = (char*)d_ws;
    size_t off = 0;
    auto alloc = [&](size_t bytes) { void* p = ws + off; off += (bytes + 255) & ~(size_t)255; return p; };
    float* modb  = (float*)alloc((size_t)NB*H6*4);
    bf16* wqkvT  = (bf16*)alloc((size_t)H3*H*2);
    bf16* wprojT = (bf16*)alloc((size_t)H*H*2);
    bf16* w1T    = (bf16*)alloc((size_t)MLPD*H*2);
    bf16* w2T    = (bf16*)alloc((size_t)H*MLPD*2);
    const size_t pers = off;

    // per-row chunk bytes: R1 (qkv|o|h overlay) = 9216, R2 (qln+kln+vt | xn overlay) = 8704
    int nchunk = 4;
    while (nchunk < 16 && pers + (size_t)(ROWS/nchunk)*(9216+8704) > ws_size) nchunk <<= 1;
    const int Rc = ROWS / nchunk;       // rows per chunk (multiple of 1024)
    const int Bc = NB / nchunk;         // batches per chunk

    char* R1 = ws + pers;                       // Rc*9216 bytes
    char* R2 = R1 + (size_t)Rc*9216;            // Rc*8704 bytes
    bf16* qkvc = (bf16*)R1;                     // Rc*3456 elems, live: qkv-gemm -> qk_ln/v_t
    bf16* oc   = (bf16*)R1;                     // Rc*1152, live: attn -> proj
    bf16* hc   = (bf16*)R1;                     // Rc*4608, live: mlp1 -> mlp2
    bf16* xnc  = (bf16*)R2;                     // Rc*1152, live: ln -> gemm (twice)
    bf16* qlnc = (bf16*)R2;                     // Bc*16*1024*96
    bf16* klnc = (bf16*)(R2 + (size_t)Rc*3072);
    bf16* vtc  = (bf16*)(R2 + (size_t)Rc*6144); // Bc*16*80*1024

    // ---- setup (once) ----
    mod_kernel<<<dim3(H6/256), 256, 0, stream>>>(c, w_mod, b_mod, modb);
    transpose_kernel<<<dim3(H3/32,  H/32),   256, 0, stream>>>(w_qkv,  wqkvT,  H,    H3);
    transpose_kernel<<<dim3(H/32,   H/32),   256, 0, stream>>>(w_proj, wprojT, H,    H);
    transpose_kernel<<<dim3(MLPD/32,H/32),   256, 0, stream>>>(w1,     w1T,    H,    MLPD);
    transpose_kernel<<<dim3(H/32,   MLPD/32),256, 0, stream>>>(w2,     w2T,    MLPD, H);

    // ---- chunked pipeline ----
    for (int ci = 0; ci < nchunk; ++ci) {
        const int row0 = ci * Rc;
        // xn = LN(x)*(1+sc_msa)+sh_msa
        ln_mod_kernel<<<dim3(Rc), 256, 0, stream>>>(x, modb, 0, H, xnc, row0);
        // qkv = xn @ w_qkv + b_qkv
        gemm_bt<0><<<dim3(H3/128, Rc/128), 256, 0, stream>>>(xnc, wqkvT, b_qkv, nullptr, nullptr, qkvc, nullptr, Rc, H3, H, 0);
        // q/k layernorm (padded 96), v transpose
        qk_ln_kernel<<<dim3(Bc*NHEAD*NTOK/4), 256, 0, stream>>>(qkvc, g_q, g_k, qlnc, klnc);
        v_transpose_kernel<<<dim3(NTOK/64, NHEAD, Bc), 256, 0, stream>>>(qkvc, vtc);
        // attention
        attn_kernel<<<dim3(NTOK/64, NHEAD, Bc), 256, 0, stream>>>(qlnc, klnc, vtc, oc);
        // x1 = x + g_msa*(o@w_proj+b_proj)   -> f32 in d_out
        gemm_bt<2><<<dim3(H/128, Rc/128), 256, 0, stream>>>(oc, wprojT, b_proj, x, modb + 2*H, nullptr, out, Rc, H, H, row0);
        // xn2 = LN(x1)*(1+sc_mlp)+sh_mlp
        ln_mod_kernel<<<dim3(Rc), 256, 0, stream>>>(out, modb, 3*H, 4*H, xnc, row0);
        // h = gelu(xn2@w1+b1)
        gemm_bt<1><<<dim3(MLPD/128, Rc/128), 256, 0, stream>>>(xnc, w1T, b1, nullptr, nullptr, hc, nullptr, Rc, MLPD, H, 0);
        // out = x1 + g_mlp*(h@w2+b2)   (f32, in-place residual)
        gemm_bt<2><<<dim3(H/128, Rc/128), 256, 0, stream>>>(hc, w2T, b2, out, modb + 5*H, nullptr, out, Rc, H, MLPD, row0);
    }
}

// Round 4
// 2143.179 us; speedup vs baseline: 1.0796x; 1.0796x over previous
//
#include <hip/hip_runtime.h>
#include <hip/hip_bf16.h>

#define H     1152
#define H3    3456
#define H6    6912
#define NTOK  1024
#define NB    16
#define NHEAD 16
#define HDIM  72
#define MLPD  4608
#define ROWS  (NB*NTOK)   // 16384
#define KSPLIT 16         // mod_kernel k-split (1152/16 = 72)

typedef __hip_bfloat16 bf16;
typedef float f32x4 __attribute__((ext_vector_type(4)));
typedef __bf16 bf16x8 __attribute__((ext_vector_type(8)));
typedef const __attribute__((address_space(1))) void* gptr_as1;
typedef __attribute__((address_space(3))) void* lptr_as3;

__device__ __forceinline__ float b2f(bf16 v){ return __bfloat162float(v); }
__device__ __forceinline__ bf16  f2b(float v){ return __float2bfloat16(v); }

// ---------------- mod stage 1: partial[ks][b][col] = sum_{k in slice} swish(c[b,k])*w_mod[k,col] ----------------
__global__ __launch_bounds__(256) void mod_partial_kernel(const float* __restrict__ c,
                                                          const float* __restrict__ w_mod,
                                                          float* __restrict__ partial) {
    const int ks = blockIdx.y;
    const int k0 = ks * (H/KSPLIT);
    __shared__ float sw[NB*(H/KSPLIT)];
    for (int i = threadIdx.x; i < NB*(H/KSPLIT); i += 256) {
        int b = i/(H/KSPLIT), k = i - b*(H/KSPLIT);
        float cv = c[b*H + k0 + k];
        sw[i] = cv / (1.f + __expf(-cv));
    }
    __syncthreads();
    const int col = blockIdx.x*256 + threadIdx.x;   // H6 = 27*256
    float acc[NB];
    #pragma unroll
    for (int b = 0; b < NB; ++b) acc[b] = 0.f;
    for (int k = 0; k < H/KSPLIT; ++k) {
        float wv = w_mod[(long)(k0+k)*H6 + col];
        #pragma unroll
        for (int b = 0; b < NB; ++b) acc[b] += sw[b*(H/KSPLIT)+k] * wv;
    }
    #pragma unroll
    for (int b = 0; b < NB; ++b) partial[((long)ks*NB + b)*H6 + col] = acc[b];
}

// ---------------- mod stage 2: mod[b][col] = sum_ks partial + b_mod[col] ----------------
__global__ __launch_bounds__(256) void mod_reduce_kernel(const float* __restrict__ partial,
                                                         const float* __restrict__ b_mod,
                                                         float* __restrict__ mod) {
    const int idx = blockIdx.x*256 + threadIdx.x;   // NB*H6 = 432*256
    const int col = idx % H6;
    float s = b_mod[col];
    #pragma unroll
    for (int ks = 0; ks < KSPLIT; ++ks) s += partial[(long)ks*NB*H6 + idx];
    mod[idx] = s;
}

// ---------------- row LN + adaLN modulate: out[local bf16] = LN(x_f32[global])*(1+sc)+sh ----------------
__global__ __launch_bounds__(256) void ln_mod_kernel(const float* __restrict__ xin,   // global base (f32)
                                                     const float* __restrict__ mod,
                                                     int sh_off, int sc_off,
                                                     bf16* __restrict__ out,          // chunk-local base
                                                     int row0) {
    const int lrow = blockIdx.x;
    const long grow = (long)row0 + lrow;
    const int b = (int)(grow >> 10);
    const int tid = threadIdx.x;
    const long ibase = grow * H;
    const long obase = (long)lrow * H;
    __shared__ float sred[8];
    float vals[5];
    float sum = 0.f, sq = 0.f;
    #pragma unroll
    for (int i = 0; i < 5; ++i) {
        int cidx = i*256 + tid;
        float v = 0.f;
        if (cidx < H) v = xin[ibase+cidx];
        vals[i] = v; sum += v; sq += v*v;
    }
    #pragma unroll
    for (int off = 32; off > 0; off >>= 1) { sum += __shfl_down(sum, off); sq += __shfl_down(sq, off); }
    int wave = tid >> 6, lane = tid & 63;
    if (lane == 0) { sred[wave] = sum; sred[4+wave] = sq; }
    __syncthreads();
    if (tid == 0) {
        sred[0] = sred[0]+sred[1]+sred[2]+sred[3];
        sred[4] = sred[4]+sred[5]+sred[6]+sred[7];
    }
    __syncthreads();
    float mean = sred[0] * (1.f/H);
    float var  = sred[4] * (1.f/H) - mean*mean;
    float rstd = rsqrtf(var + 1e-6f);
    const float* mrow = mod + b*H6;
    #pragma unroll
    for (int i = 0; i < 5; ++i) {
        int cidx = i*256 + tid;
        if (cidx < H) {
            float y = (vals[i]-mean)*rstd;
            out[obase+cidx] = f2b(y * (1.f + mrow[sc_off+cidx]) + mrow[sh_off+cidx]);
        }
    }
}

// ---------------- f32 -> bf16 transpose (R,C)->(C,R), dims multiple of 32 ----------------
__global__ __launch_bounds__(256) void transpose_kernel(const float* __restrict__ in,
                                                        bf16* __restrict__ out, int R, int C) {
    __shared__ bf16 tile[32][33];
    int c0 = blockIdx.x*32, r0 = blockIdx.y*32;
    int tx = threadIdx.x & 31, ty = threadIdx.x >> 5;
    for (int j = ty; j < 32; j += 8) tile[j][tx] = f2b(in[(long)(r0+j)*C + c0 + tx]);
    __syncthreads();
    for (int j = ty; j < 32; j += 8) out[(long)(c0+j)*R + r0 + tx] = tile[tx][j];
}

// ---------------- m97-style GEMM: A[local M,K]bf16 @ BT[N,K]^T bf16 + bias(f32) ----------------
// EPI 0: C[local] = acc+bias (bf16)
// EPI 1: C[local] = gelu(acc+bias) (bf16)
// EPI 2: Cf[global,f32] = res_f32[global] + gate*(acc+bias)
template<int EPI>
__global__ __launch_bounds__(256) void gemm_bt(const bf16* __restrict__ A, const bf16* __restrict__ BT,
                                               const float* __restrict__ bias,
                                               const float* __restrict__ res, const float* __restrict__ gate,
                                               bf16* __restrict__ C, float* __restrict__ Cf,
                                               int M, int N, int K, int row0) {
    __shared__ __align__(16) bf16 As[128*64];
    __shared__ __align__(16) bf16 Bs[128*64];
    const int tid  = threadIdx.x;
    const int wave = tid >> 6, lane = tid & 63;
    const int wm = wave & 1, wn = wave >> 1;
    const int col = lane & 15, quad = lane >> 4;
    f32x4 acc[4][4];
    #pragma unroll
    for (int i = 0; i < 4; ++i)
        #pragma unroll
        for (int j = 0; j < 4; ++j) acc[i][j] = (f32x4){0.f,0.f,0.f,0.f};

    const long arow0 = (long)blockIdx.y * 128;
    const long brow0 = (long)blockIdx.x * 128;
    const int  srow  = tid >> 3;
    const int  scol  = (tid & 7) * 8;
    const bf16* Ag = A + (arow0 + srow)*(long)K + scol;
    const bf16* Bg = BT + (brow0 + srow)*(long)K + scol;
    bf16* Asl = As + tid*8;
    bf16* Bsl = Bs + tid*8;

    for (int k0 = 0; k0 < K; k0 += 64) {
        __syncthreads();
        #pragma unroll
        for (int i = 0; i < 4; ++i) {
            __builtin_amdgcn_global_load_lds((gptr_as1)(Ag + (long)i*32*K + k0), (lptr_as3)(Asl + i*2048), 16, 0, 0);
            __builtin_amdgcn_global_load_lds((gptr_as1)(Bg + (long)i*32*K + k0), (lptr_as3)(Bsl + i*2048), 16, 0, 0);
        }
        __syncthreads();
        #pragma unroll
        for (int kk = 0; kk < 64; kk += 32) {
            bf16x8 af[4], bfr[4];
            #pragma unroll
            for (int mt = 0; mt < 4; ++mt) af[mt]  = *(const bf16x8*)&As[(wm*64+mt*16+col)*64 + kk + quad*8];
            #pragma unroll
            for (int nt = 0; nt < 4; ++nt) bfr[nt] = *(const bf16x8*)&Bs[(wn*64+nt*16+col)*64 + kk + quad*8];
            #pragma unroll
            for (int mt = 0; mt < 4; ++mt)
                #pragma unroll
                for (int nt = 0; nt < 4; ++nt)
                    acc[mt][nt] = __builtin_amdgcn_mfma_f32_16x16x32_bf16(af[mt], bfr[nt], acc[mt][nt], 0, 0, 0);
        }
    }

    #pragma unroll
    for (int mt = 0; mt < 4; ++mt) {
        #pragma unroll
        for (int nt = 0; nt < 4; ++nt) {
            const int colg = (int)brow0 + wn*64 + nt*16 + col;
            const float bv = bias[colg];
            #pragma unroll
            for (int r = 0; r < 4; ++r) {
                const long rowg = arow0 + wm*64 + mt*16 + quad*4 + r;
                float v = acc[mt][nt][r] + bv;
                if (EPI == 1) {
                    v = 0.5f*v*(1.f + tanhf(0.7978845608028654f*(v + 0.044715f*v*v*v)));
                    C[rowg*(long)N + colg] = f2b(v);
                } else if (EPI == 2) {
                    const long grow = row0 + rowg;
                    float g = gate[(int)(grow>>10)*H6 + colg];
                    Cf[grow*(long)N + colg] = res[grow*(long)N + colg] + g*v;
                } else {
                    C[rowg*(long)N + colg] = f2b(v);
                }
            }
        }
    }
}

// ---------------- per-head LN of q,k (dim 72, bf16 in/out) -> padded [b'][NH][N][96] ----------------
__device__ __forceinline__ void ln72(const bf16* __restrict__ src, const float* __restrict__ gw,
                                     float scale, bf16* __restrict__ dst, int lane) {
    const int i1 = 64 + (lane & 7);
    float e0 = b2f(src[lane]);
    float e1 = (lane < 8) ? b2f(src[i1]) : 0.f;
    float s = e0 + e1;
    #pragma unroll
    for (int off = 32; off > 0; off >>= 1) s += __shfl_xor(s, off);
    float mean = s * (1.f/72.f);
    float d0 = e0 - mean;
    float d1 = (lane < 8) ? (e1 - mean) : 0.f;
    float sq = d0*d0 + d1*d1;
    #pragma unroll
    for (int off = 32; off > 0; off >>= 1) sq += __shfl_xor(sq, off);
    float rstd = rsqrtf(sq*(1.f/72.f) + 1e-6f);
    dst[lane] = f2b(d0*rstd*gw[lane]*scale);
    if (lane < 32) {
        float y1 = (lane < 8) ? d1*rstd*gw[i1]*scale : 0.f;
        dst[64+lane] = f2b(y1);
    }
}

__global__ __launch_bounds__(256) void qk_ln_kernel(const bf16* __restrict__ qkv,  // chunk-local
                                                    const float* __restrict__ g_q, const float* __restrict__ g_k,
                                                    bf16* __restrict__ qln, bf16* __restrict__ kln) {
    const int wave = threadIdx.x >> 6, lane = threadIdx.x & 63;
    const long g  = (long)blockIdx.x*4 + wave;     // < Bc*NHEAD*NTOK
    const int  n  = (int)(g & 1023);
    const long bh = g >> 10;                        // local b*16 + h
    const int  h  = (int)(bh & 15);
    const int  b  = (int)(bh >> 4);
    const bf16* src = qkv + ((long)b*NTOK + n)*H3 + h*HDIM;
    ln72(src,     g_q, 0.11785113019775793f, qln + (bh*NTOK + n)*96, lane);   // q * HD^-0.5
    ln72(src + H, g_k, 1.f,                  kln + (bh*NTOK + n)*96, lane);
}

// ---------------- V -> VT [b'][NH][80][NTOK] (pad rows 72..79 = 0), bf16 ----------------
__global__ __launch_bounds__(256) void v_transpose_kernel(const bf16* __restrict__ qkv, bf16* __restrict__ vt) {
    const int n0 = blockIdx.x*64;
    const int h = blockIdx.y, b = blockIdx.z;      // b local
    __shared__ bf16 tile[64][80];
    const long srcbase = ((long)b*NTOK + n0)*H3 + 2*H + h*HDIM;
    for (int idx = threadIdx.x; idx < 64*72; idx += 256) {
        int n = idx/72, d = idx - n*72;
        tile[n][d] = qkv[srcbase + (long)n*H3 + d];
    }
    for (int idx = threadIdx.x; idx < 64*8; idx += 256) {
        int n = idx >> 3, d = idx & 7;
        tile[n][72+d] = f2b(0.f);
    }
    __syncthreads();
    const long dstbase = ((long)(b*NHEAD + h)*80)*NTOK + n0;
    for (int idx = threadIdx.x; idx < 80*64; idx += 256) {
        int d = idx >> 6, n = idx & 63;
        vt[dstbase + (long)d*NTOK + n] = tile[n][d];
    }
}

// ---------------- flash attention: wave = 16 q rows, kv tiles of 32 (chunk-local, bf16) ----------------
__global__ __launch_bounds__(256) void attn_kernel(const bf16* __restrict__ qln, const bf16* __restrict__ kln,
                                                   const bf16* __restrict__ vt, bf16* __restrict__ o) {
    const int wave = threadIdx.x >> 6, lane = threadIdx.x & 63;
    const int col = lane & 15, quad = lane >> 4;
    const int b = blockIdx.z, h = blockIdx.y;      // b local
    const long bh = b*NHEAD + h;
    const int q0 = blockIdx.x*64 + wave*16;
    const bf16* qb = qln + bh*NTOK*96;
    const bf16* kb = kln + bh*NTOK*96;
    const bf16* vb = vt  + bh*80*NTOK;
    __shared__ __align__(16) bf16 Pl[4][16*32];
    bf16* pw = &Pl[wave][0];

    bf16x8 qf[3];
    #pragma unroll
    for (int ks = 0; ks < 3; ++ks) qf[ks] = *(const bf16x8*)&qb[(q0+col)*96 + ks*32 + quad*8];

    f32x4 oacc[5];
    #pragma unroll
    for (int i = 0; i < 5; ++i) oacc[i] = (f32x4){0.f,0.f,0.f,0.f};
    float mrow[4], lrow[4];
    #pragma unroll
    for (int r = 0; r < 4; ++r) { mrow[r] = -1e30f; lrow[r] = 0.f; }

    for (int kv0 = 0; kv0 < NTOK; kv0 += 32) {
        f32x4 s0 = (f32x4){0.f,0.f,0.f,0.f}, s1 = (f32x4){0.f,0.f,0.f,0.f};
        #pragma unroll
        for (int ks = 0; ks < 3; ++ks) {
            bf16x8 k0f = *(const bf16x8*)&kb[(kv0+col)*96    + ks*32 + quad*8];
            bf16x8 k1f = *(const bf16x8*)&kb[(kv0+16+col)*96 + ks*32 + quad*8];
            s0 = __builtin_amdgcn_mfma_f32_16x16x32_bf16(qf[ks], k0f, s0, 0, 0, 0);
            s1 = __builtin_amdgcn_mfma_f32_16x16x32_bf16(qf[ks], k1f, s1, 0, 0, 0);
        }
        float alpha[4];
        #pragma unroll
        for (int r = 0; r < 4; ++r) {
            float tm = fmaxf(s0[r], s1[r]);
            #pragma unroll
            for (int off = 1; off < 16; off <<= 1) tm = fmaxf(tm, __shfl_xor(tm, off));
            float mn = fmaxf(mrow[r], tm);
            alpha[r] = __expf(mrow[r] - mn);
            float p0 = __expf(s0[r] - mn);
            float p1 = __expf(s1[r] - mn);
            float ts = p0 + p1;
            #pragma unroll
            for (int off = 1; off < 16; off <<= 1) ts += __shfl_xor(ts, off);
            lrow[r] = lrow[r]*alpha[r] + ts;
            mrow[r] = mn;
            pw[(quad*4+r)*32 + col]      = f2b(p0);
            pw[(quad*4+r)*32 + 16 + col] = f2b(p1);
        }
        #pragma unroll
        for (int i = 0; i < 5; ++i)
            #pragma unroll
            for (int r = 0; r < 4; ++r) oacc[i][r] *= alpha[r];
        asm volatile("s_waitcnt lgkmcnt(0)" ::: "memory");
        bf16x8 pf = *(const bf16x8*)&pw[col*32 + quad*8];
        #pragma unroll
        for (int nt = 0; nt < 5; ++nt) {
            bf16x8 vf = *(const bf16x8*)&vb[(nt*16+col)*NTOK + kv0 + quad*8];
            oacc[nt] = __builtin_amdgcn_mfma_f32_16x16x32_bf16(pf, vf, oacc[nt], 0, 0, 0);
        }
    }
    float inv[4];
    #pragma unroll
    for (int r = 0; r < 4; ++r) inv[r] = 1.f / lrow[r];
    #pragma unroll
    for (int nt = 0; nt < 5; ++nt) {
        int d = nt*16 + col;
        if (d < HDIM) {
            #pragma unroll
            for (int r = 0; r < 4; ++r) {
                int qrow = q0 + quad*4 + r;
                o[((long)b*NTOK + qrow)*H + h*HDIM + d] = f2b(oacc[nt][r]*inv[r]);
            }
        }
    }
}

extern "C" void kernel_launch(void* const* d_in, const int* in_sizes, int n_in,
                              void* d_out, int out_size, void* d_ws, size_t ws_size,
                              hipStream_t stream) {
    const float* x      = (const float*)d_in[0];
    const float* c      = (const float*)d_in[1];
    const float* w_mod  = (const float*)d_in[2];
    const float* b_mod  = (const float*)d_in[3];
    const float* w_qkv  = (const float*)d_in[4];
    const float* b_qkv  = (const float*)d_in[5];
    const float* g_q    = (const float*)d_in[6];
    const float* g_k    = (const float*)d_in[7];
    const float* w_proj = (const float*)d_in[8];
    const float* b_proj = (const float*)d_in[9];
    const float* w1     = (const float*)d_in[10];
    const float* b1     = (const float*)d_in[11];
    const float* w2     = (const float*)d_in[12];
    const float* b2     = (const float*)d_in[13];
    float* out = (float*)d_out;   // f32; also serves as x1 (residual after attn branch)

    // ---- workspace layout (runtime-sized, chunked row pipeline) ----
    char* ws = (char*)d_ws;
    size_t off = 0;
    auto alloc = [&](size_t bytes) { void* p = ws + off; off += (bytes + 255) & ~(size_t)255; return p; };
    float* modb  = (float*)alloc((size_t)NB*H6*4);
    bf16* wqkvT  = (bf16*)alloc((size_t)H3*H*2);
    bf16* wprojT = (bf16*)alloc((size_t)H*H*2);
    bf16* w1T    = (bf16*)alloc((size_t)MLPD*H*2);
    bf16* w2T    = (bf16*)alloc((size_t)H*MLPD*2);
    const size_t pers = off;

    // per-row chunk bytes: R1 (qkv|o|h overlay) = 9216, R2 (qln+kln+vt | xn overlay) = 8704
    int nchunk = 4;
    while (nchunk < 16 && pers + (size_t)(ROWS/nchunk)*(9216+8704) > ws_size) nchunk <<= 1;
    const int Rc = ROWS / nchunk;       // rows per chunk (multiple of 1024)
    const int Bc = NB / nchunk;         // batches per chunk

    char* R1 = ws + pers;                       // Rc*9216 bytes
    char* R2 = R1 + (size_t)Rc*9216;            // Rc*8704 bytes
    bf16* qkvc = (bf16*)R1;                     // Rc*3456 elems, live: qkv-gemm -> qk_ln/v_t
    bf16* oc   = (bf16*)R1;                     // Rc*1152, live: attn -> proj
    bf16* hc   = (bf16*)R1;                     // Rc*4608, live: mlp1 -> mlp2
    bf16* xnc  = (bf16*)R2;                     // Rc*1152, live: ln -> gemm (twice)
    bf16* qlnc = (bf16*)R2;                     // Bc*16*1024*96
    bf16* klnc = (bf16*)(R2 + (size_t)Rc*3072);
    bf16* vtc  = (bf16*)(R2 + (size_t)Rc*6144); // Bc*16*80*1024
    float* modp = (float*)R1;                   // mod partials (KSPLIT*NB*H6*4 = 7.1MB <= R1 9.4MB),
                                                // dead before first chunk kernel writes R1

    // ---- setup (once) ----
    mod_partial_kernel<<<dim3(H6/256, KSPLIT), 256, 0, stream>>>(c, w_mod, modp);
    mod_reduce_kernel<<<dim3(NB*H6/256), 256, 0, stream>>>(modp, b_mod, modb);
    transpose_kernel<<<dim3(H3/32,  H/32),   256, 0, stream>>>(w_qkv,  wqkvT,  H,    H3);
    transpose_kernel<<<dim3(H/32,   H/32),   256, 0, stream>>>(w_proj, wprojT, H,    H);
    transpose_kernel<<<dim3(MLPD/32,H/32),   256, 0, stream>>>(w1,     w1T,    H,    MLPD);
    transpose_kernel<<<dim3(H/32,   MLPD/32),256, 0, stream>>>(w2,     w2T,    MLPD, H);

    // ---- chunked pipeline ----
    for (int ci = 0; ci < nchunk; ++ci) {
        const int row0 = ci * Rc;
        // xn = LN(x)*(1+sc_msa)+sh_msa
        ln_mod_kernel<<<dim3(Rc), 256, 0, stream>>>(x, modb, 0, H, xnc, row0);
        // qkv = xn @ w_qkv + b_qkv
        gemm_bt<0><<<dim3(H3/128, Rc/128), 256, 0, stream>>>(xnc, wqkvT, b_qkv, nullptr, nullptr, qkvc, nullptr, Rc, H3, H, 0);
        // q/k layernorm (padded 96), v transpose
        qk_ln_kernel<<<dim3(Bc*NHEAD*NTOK/4), 256, 0, stream>>>(qkvc, g_q, g_k, qlnc, klnc);
        v_transpose_kernel<<<dim3(NTOK/64, NHEAD, Bc), 256, 0, stream>>>(qkvc, vtc);
        // attention
        attn_kernel<<<dim3(NTOK/64, NHEAD, Bc), 256, 0, stream>>>(qlnc, klnc, vtc, oc);
        // x1 = x + g_msa*(o@w_proj+b_proj)   -> f32 in d_out
        gemm_bt<2><<<dim3(H/128, Rc/128), 256, 0, stream>>>(oc, wprojT, b_proj, x, modb + 2*H, nullptr, out, Rc, H, H, row0);
        // xn2 = LN(x1)*(1+sc_mlp)+sh_mlp
        ln_mod_kernel<<<dim3(Rc), 256, 0, stream>>>(out, modb, 3*H, 4*H, xnc, row0);
        // h = gelu(xn2@w1+b1)
        gemm_bt<1><<<dim3(MLPD/128, Rc/128), 256, 0, stream>>>(xnc, w1T, b1, nullptr, nullptr, hc, nullptr, Rc, MLPD, H, 0);
        // out = x1 + g_mlp*(h@w2+b2)   (f32, in-place residual)
        gemm_bt<2><<<dim3(H/128, Rc/128), 256, 0, stream>>>(hc, w2T, b2, out, modb + 5*H, nullptr, out, Rc, H, MLPD, row0);
    }
}